// Round 2
// baseline (1061.980 us; speedup 1.0000x reference)
//
#include <hip/hip_runtime.h>
#include <hip/hip_bf16.h>
#include <cstdint>
#include <cstddef>

#define NB   8
#define CIN  128
#define COUT 64
#define HH   128
#define WWD  128
#define NPIX (NB*HH*WWD)   // 131072

typedef __hip_bfloat16 bf16;

// float -> bf16 bits, round-to-nearest-even
__device__ __forceinline__ unsigned short f2bf(float f){
  unsigned u = __float_as_uint(f);
  unsigned r = (u + 0x7fffu + ((u >> 16) & 1u)) >> 16;
  return (unsigned short)r;
}

// ---------------- Kernel 1: three 1x1 convs, fp32 compute ----------------
// Q,K stored fp32 channel-last; V stored bf16 channel-last.
__device__ __forceinline__ void do_mat_f32(const float* __restrict__ xp,
                                           const float* __restrict__ W,
                                           float* __restrict__ y)
{
  float acc[COUT];
  #pragma unroll
  for (int o = 0; o < COUT; ++o) acc[o] = 0.f;

  for (int c = 0; c < CIN; c += 4) {
    float xv0 = xp[(size_t)(c+0) << 14];
    float xv1 = xp[(size_t)(c+1) << 14];
    float xv2 = xp[(size_t)(c+2) << 14];
    float xv3 = xp[(size_t)(c+3) << 14];
    #pragma unroll
    for (int o = 0; o < COUT; ++o) {
      float a = acc[o];
      a = fmaf(W[o*CIN + c + 0], xv0, a);
      a = fmaf(W[o*CIN + c + 1], xv1, a);
      a = fmaf(W[o*CIN + c + 2], xv2, a);
      a = fmaf(W[o*CIN + c + 3], xv3, a);
      acc[o] = a;
    }
  }
  #pragma unroll
  for (int o = 0; o < COUT; o += 4) {
    float4 pk = make_float4(acc[o+0], acc[o+1], acc[o+2], acc[o+3]);
    *reinterpret_cast<float4*>(y + o) = pk;
  }
}

__device__ __forceinline__ void do_mat_bf16(const float* __restrict__ xp,
                                            const float* __restrict__ W,
                                            bf16* __restrict__ y)
{
  float acc[COUT];
  #pragma unroll
  for (int o = 0; o < COUT; ++o) acc[o] = 0.f;

  for (int c = 0; c < CIN; c += 4) {
    float xv0 = xp[(size_t)(c+0) << 14];
    float xv1 = xp[(size_t)(c+1) << 14];
    float xv2 = xp[(size_t)(c+2) << 14];
    float xv3 = xp[(size_t)(c+3) << 14];
    #pragma unroll
    for (int o = 0; o < COUT; ++o) {
      float a = acc[o];
      a = fmaf(W[o*CIN + c + 0], xv0, a);
      a = fmaf(W[o*CIN + c + 1], xv1, a);
      a = fmaf(W[o*CIN + c + 2], xv2, a);
      a = fmaf(W[o*CIN + c + 3], xv3, a);
      acc[o] = a;
    }
  }
  #pragma unroll
  for (int o = 0; o < COUT; o += 8) {
    uint4 pk;
    pk.x = (unsigned)f2bf(acc[o+0]) | ((unsigned)f2bf(acc[o+1]) << 16);
    pk.y = (unsigned)f2bf(acc[o+2]) | ((unsigned)f2bf(acc[o+3]) << 16);
    pk.z = (unsigned)f2bf(acc[o+4]) | ((unsigned)f2bf(acc[o+5]) << 16);
    pk.w = (unsigned)f2bf(acc[o+6]) | ((unsigned)f2bf(acc[o+7]) << 16);
    *reinterpret_cast<uint4*>(y + o) = pk;
  }
}

__global__ __launch_bounds__(256) void conv1x1_k(
    const float* __restrict__ x,  const float* __restrict__ W1,
    const float* __restrict__ W2, const float* __restrict__ W3,
    float* __restrict__ y1, float* __restrict__ y2, bf16* __restrict__ y3)
{
  int p  = blockIdx.x * 256 + threadIdx.x;   // global pixel
  int n  = p >> 14;
  int hw = p & 16383;
  const float* xp = x + ((size_t)n * CIN << 14) + hw;
  do_mat_f32 (xp, W1, y1 + (size_t)p * COUT);
  do_mat_f32 (xp, W2, y2 + (size_t)p * COUT);
  do_mat_bf16(xp, W3, y3 + (size_t)p * COUT);
}

// ---------------- Kernel 2: logits -> softmax -> weighting, one wave per pixel ----------
__global__ __launch_bounds__(256) void attn_k(
    const float* __restrict__ y1, const float* __restrict__ y2,
    const bf16* __restrict__ y3, float* __restrict__ out)
{
  __shared__ float qs[4][64];
  __shared__ float wgs[4][81];

  int tid  = threadIdx.x;
  int wv   = tid >> 6;
  int lane = tid & 63;
  int p    = blockIdx.x * 4 + wv;            // pixel for this wave
  int n    = p >> 14;
  int hw   = p & 16383;
  int h    = hw >> 7;
  int w0   = hw & 127;

  // stage Q row (64 channels, fp32) into LDS
  qs[wv][lane] = y1[(size_t)p * 64 + lane];
  __syncthreads();

  // ---- Phase A: logits, lane <-> offset index k ----
  auto dot_at = [&](int kk, bool on) -> float {
    int dh = kk / 9, dw = kk - dh * 9;
    int hs = h  + 2*dh - 8;
    int ws = w0 + 2*dw - 8;
    bool valid = on && ((unsigned)hs < 128u) && ((unsigned)ws < 128u);
    int pk = valid ? ((n << 14) + (hs << 7) + ws) : p;   // clamp to self when invalid
    const float4* b = reinterpret_cast<const float4*>(y2 + (size_t)pk * 64);
    float d = 0.f;
    #pragma unroll
    for (int c = 0; c < 64; c += 8) {
      float4 k0 = b[(c >> 2) + 0];
      float4 k1 = b[(c >> 2) + 1];
      float4 qa = *reinterpret_cast<const float4*>(&qs[wv][c]);
      float4 qb = *reinterpret_cast<const float4*>(&qs[wv][c + 4]);
      d += qa.x * k0.x + qa.y * k0.y + qa.z * k0.z + qa.w * k0.w;
      d += qb.x * k1.x + qb.y * k1.y + qb.z * k1.z + qb.w * k1.w;
    }
    // zero-padded reference: out-of-bounds window -> dot with zeros -> logit exactly 0
    return valid ? d : 0.f;
  };

  float l0  = dot_at(lane, true);            // k = lane (0..63, all < 81)
  bool has1 = lane < 17;                      // k = 64+lane (64..80)
  float l1  = dot_at(64 + lane, has1);

  // ---- softmax over 81 (wave reduction) ----
  float mx = has1 ? fmaxf(l0, l1) : l0;
  #pragma unroll
  for (int off = 32; off >= 1; off >>= 1) mx = fmaxf(mx, __shfl_xor(mx, off, 64));
  float e0 = __expf(l0 - mx);
  float e1 = has1 ? __expf(l1 - mx) : 0.f;
  float s  = e0 + e1;
  #pragma unroll
  for (int off = 32; off >= 1; off >>= 1) s += __shfl_xor(s, off, 64);
  float inv = 1.f / s;
  wgs[wv][lane] = e0 * inv;
  if (has1) wgs[wv][64 + lane] = e1 * inv;
  __syncthreads();

  // ---- Phase B: weighting, lane <-> output channel ----
  float acc = 0.f;
  const bf16* vb = y3 + lane;
  #pragma unroll
  for (int k = 0; k < 81; ++k) {
    const int dh = k / 9, dw = k % 9;        // compile-time after unroll
    int hs = h  + 2*dh - 8;
    int ws = w0 + 2*dw - 8;
    if (((unsigned)hs < 128u) & ((unsigned)ws < 128u)) {   // wave-uniform branch
      float wk = wgs[wv][k];
      int pk = (n << 14) + (hs << 7) + ws;
      float vv = __uint_as_float(
          ((unsigned)*(const unsigned short*)(vb + ((size_t)pk << 6))) << 16);
      acc = fmaf(wk, vv, acc);
    }
  }
  // out[n][c=lane][h][w]  (scattered across lanes; accepted cost for now)
  out[(((size_t)(n * 64 + lane)) << 14) + hw] = acc;
}

// ---------------- launcher ----------------
extern "C" void kernel_launch(void* const* d_in, const int* in_sizes, int n_in,
                              void* d_out, int out_size, void* d_ws, size_t ws_size,
                              hipStream_t stream)
{
  const float* x  = (const float*)d_in[0];
  const float* W1 = (const float*)d_in[1];
  const float* W2 = (const float*)d_in[2];
  const float* W3 = (const float*)d_in[3];

  float* y1 = (float*)d_ws;                     // Q fp32 [NPIX][64], 33.55 MB
  float* y2 = y1 + (size_t)NPIX * COUT;         // K fp32 [NPIX][64], 33.55 MB
  bf16*  y3 = (bf16*)(y2 + (size_t)NPIX * COUT);// V bf16 [NPIX][64], 16.78 MB

  float* outp = (float*)d_out;

  conv1x1_k<<<NPIX / 256, 256, 0, stream>>>(x, W1, W2, W3, y1, y2, y3);
  attn_k  <<<NPIX / 4,   256, 0, stream>>>(y1, y2, y3, outp);
}

// Round 3
// 1021.579 us; speedup vs baseline: 1.0395x; 1.0395x over previous
//
#include <hip/hip_runtime.h>
#include <hip/hip_bf16.h>
#include <cstdint>
#include <cstddef>

#define NB   8
#define CIN  128
#define COUT 64
#define HH   128
#define WWD  128
#define NPIX (NB*HH*WWD)   // 131072
#define PLANE NPIX

typedef __hip_bfloat16 bf16;
typedef _Float16 f16;

// float -> bf16 bits, round-to-nearest-even
__device__ __forceinline__ unsigned short f2bf(float f){
  unsigned u = __float_as_uint(f);
  return (unsigned short)((u + 0x7fffu + ((u >> 16) & 1u)) >> 16);
}
__device__ __forceinline__ float bf2f(unsigned short h){
  return __uint_as_float(((unsigned)h) << 16);
}
// force a (wave-uniform) pointer into SGPRs so W reads become s_loads
__device__ __forceinline__ const float* uniform_ptr(const float* p){
  uint64_t v = (uint64_t)(uintptr_t)p;
  uint32_t lo = __builtin_amdgcn_readfirstlane((uint32_t)v);
  uint32_t hi = __builtin_amdgcn_readfirstlane((uint32_t)(v >> 32));
  return (const float*)(uintptr_t)(((uint64_t)hi << 32) | lo);
}

// ============ Kernel 1: 3x 1x1 conv as GEMM, channel-major outputs ============
// block = 256 thr = 4 waves; block handles 128 px; wave w does o-chunks {w, w+4, w+8}
// chunk = 16 outputs; thread handles 2 px (lane, lane+64). W s_load x4 feeds 8 FMAs.
__global__ __launch_bounds__(256) void conv_k(
    const float* __restrict__ x,  const float* __restrict__ W1,
    const float* __restrict__ W2, const float* __restrict__ W3,
    float* __restrict__ Qp, float* __restrict__ Kp, unsigned short* __restrict__ Vp)
{
  int lane = threadIdx.x & 63;
  int wv   = threadIdx.x >> 6;
  int pxt  = blockIdx.x * 128;
  int n    = pxt >> 14;                       // uniform per block
  int hwA  = (pxt & 16383) + lane;
  int hwB  = hwA + 64;
  const float* xb = x + (size_t)n * (CIN * 16384);

  for (int pass = 0; pass < 3; ++pass) {
    int chunk = wv + pass * 4;                // 0..11
    int mat   = chunk >> 2;                   // 0=Q,1=K,2=V
    int ol    = (chunk & 3) * 16;
    const float* Wp = (mat == 0 ? W1 : (mat == 1 ? W2 : W3));
    Wp = uniform_ptr(Wp + ol * CIN);

    float accA[16], accB[16];
    #pragma unroll
    for (int o = 0; o < 16; ++o) { accA[o] = 0.f; accB[o] = 0.f; }

    for (int c = 0; c < CIN; c += 4) {
      float xa0 = xb[(c+0)*16384 + hwA];
      float xa1 = xb[(c+1)*16384 + hwA];
      float xa2 = xb[(c+2)*16384 + hwA];
      float xa3 = xb[(c+3)*16384 + hwA];
      float xb0 = xb[(c+0)*16384 + hwB];
      float xb1 = xb[(c+1)*16384 + hwB];
      float xb2 = xb[(c+2)*16384 + hwB];
      float xb3 = xb[(c+3)*16384 + hwB];
      #pragma unroll
      for (int o = 0; o < 16; ++o) {
        float w0 = Wp[o*CIN + c + 0];
        float w1 = Wp[o*CIN + c + 1];
        float w2 = Wp[o*CIN + c + 2];
        float w3 = Wp[o*CIN + c + 3];
        accA[o] = fmaf(w0, xa0, fmaf(w1, xa1, fmaf(w2, xa2, fmaf(w3, xa3, accA[o]))));
        accB[o] = fmaf(w0, xb0, fmaf(w1, xb1, fmaf(w2, xb2, fmaf(w3, xb3, accB[o]))));
      }
    }

    int pxA = pxt + lane, pxB = pxA + 64;
    if (mat == 0) {
      #pragma unroll
      for (int o = 0; o < 16; ++o) {
        Qp[(ol+o)*PLANE + pxA] = accA[o];
        Qp[(ol+o)*PLANE + pxB] = accB[o];
      }
    } else if (mat == 1) {
      #pragma unroll
      for (int o = 0; o < 16; ++o) {
        Kp[(ol+o)*PLANE + pxA] = accA[o];
        Kp[(ol+o)*PLANE + pxB] = accB[o];
      }
    } else {
      #pragma unroll
      for (int o = 0; o < 16; ++o) {
        Vp[(ol+o)*PLANE + pxA] = f2bf(accA[o]);
        Vp[(ol+o)*PLANE + pxB] = f2bf(accB[o]);
      }
    }
  }
}

// ============ Kernel 2: logits + online softmax stats, thread = pixel ============
__global__ __launch_bounds__(256) void logits_k(
    const float* __restrict__ Qp, const float* __restrict__ Kp,
    f16* __restrict__ Lp, float* __restrict__ Mp, float* __restrict__ Sp)
{
  int px = blockIdx.x * 256 + threadIdx.x;
  int n = px >> 14, hw = px & 16383, h = hw >> 7, w = hw & 127;

  float q[64];
  #pragma unroll
  for (int c = 0; c < 64; ++c) q[c] = Qp[c*PLANE + px];   // 64 coalesced loads

  float m = -1e30f, s = 0.f;
  int nb = n << 14;

  for (int dh = 0; dh < 9; ++dh) {
    int hs = h + 2*dh - 8;
    bool rv = ((unsigned)hs < 128u);          // wave-uniform (64 | row width)
    for (int dw = 0; dw < 9; ++dw) {
      float l = 0.f;
      if (rv) {
        int ws_ = w + 2*dw - 8;               // per-lane
        int pxn = nb + (hs << 7) + ws_;
        const float* kp = Kp + pxn;           // in-bounds memory even if ws_ OOB
        float d0 = 0.f, d1 = 0.f, d2 = 0.f, d3 = 0.f;
        #pragma unroll
        for (int c = 0; c < 64; c += 4) {
          d0 = fmaf(q[c+0], kp[(c+0)*PLANE], d0);
          d1 = fmaf(q[c+1], kp[(c+1)*PLANE], d1);
          d2 = fmaf(q[c+2], kp[(c+2)*PLANE], d2);
          d3 = fmaf(q[c+3], kp[(c+3)*PLANE], d3);
        }
        float d = (d0 + d1) + (d2 + d3);
        l = ((unsigned)ws_ < 128u) ? d : 0.f; // OOB window -> logit exactly 0 (cndmask)
      }
      float mn = fmaxf(m, l);                 // online softmax
      s = s * __expf(m - mn) + __expf(l - mn);
      m = mn;
      Lp[(dh*9 + dw)*PLANE + px] = (f16)l;    // coalesced 2B store
    }
  }
  Mp[px] = m;
  Sp[px] = 1.f / s;
}

// ============ Kernel 3: apply weights to V, thread = (pixel, 16-ch group) ============
__global__ __launch_bounds__(256) void apply_k(
    const unsigned short* __restrict__ Vp, const f16* __restrict__ Lp,
    const float* __restrict__ Mp, const float* __restrict__ Sp,
    float* __restrict__ out)
{
  int b  = blockIdx.x;
  int px = (b & 511) * 256 + threadIdx.x;
  int c0 = (b >> 9) * 16;
  int n = px >> 14, hw = px & 16383, h = hw >> 7, w = hw & 127;

  float m = Mp[px], sinv = Sp[px];
  float acc[16];
  #pragma unroll
  for (int j = 0; j < 16; ++j) acc[j] = 0.f;
  int nb = n << 14;

  for (int dh = 0; dh < 9; ++dh) {
    int hs = h + 2*dh - 8;
    if ((unsigned)hs >= 128u) continue;       // OOB row: V contributes 0
    for (int dw = 0; dw < 9; ++dw) {
      int ws_ = w + 2*dw - 8;
      bool val = ((unsigned)ws_ < 128u);
      float l = (float)Lp[(dh*9 + dw)*PLANE + px];
      float wgt = val ? __expf(l - m) * sinv : 0.f;
      int pxn = val ? (nb + (hs << 7) + ws_) : px;   // clamp: never multiply junk
      const unsigned short* vp = Vp + (size_t)c0*PLANE + pxn;
      #pragma unroll
      for (int j = 0; j < 16; ++j)
        acc[j] = fmaf(wgt, bf2f(vp[(size_t)j*PLANE]), acc[j]);
    }
  }
  size_t ob = ((size_t)(n*COUT + c0) << 14) + hw;    // NCHW, coalesced
  #pragma unroll
  for (int j = 0; j < 16; ++j) out[ob + (size_t)j*16384] = acc[j];
}

// ---------------- launcher ----------------
extern "C" void kernel_launch(void* const* d_in, const int* in_sizes, int n_in,
                              void* d_out, int out_size, void* d_ws, size_t ws_size,
                              hipStream_t stream)
{
  const float* x  = (const float*)d_in[0];
  const float* W1 = (const float*)d_in[1];
  const float* W2 = (const float*)d_in[2];
  const float* W3 = (const float*)d_in[3];

  // ws layout (106.2 MB total):
  float* Qp = (float*)d_ws;                               // [64][NPIX] f32
  float* Kp = Qp + (size_t)64*NPIX;                       // [64][NPIX] f32
  unsigned short* Vp = (unsigned short*)(Kp + (size_t)64*NPIX); // [64][NPIX] bf16
  f16*   Lp = (f16*)(Vp + (size_t)64*NPIX);               // [81][NPIX] f16 logits
  float* Mp = (float*)(Lp + (size_t)81*NPIX);             // [NPIX] row max
  float* Sp = Mp + NPIX;                                  // [NPIX] 1/sum

  float* outp = (float*)d_out;

  conv_k  <<<NPIX/128,       256, 0, stream>>>(x, W1, W2, W3, Qp, Kp, Vp);
  logits_k<<<NPIX/256,       256, 0, stream>>>(Qp, Kp, Lp, Mp, Sp);
  apply_k <<<(NPIX/256)*4,   256, 0, stream>>>(Vp, Lp, Mp, Sp, outp);
}

// Round 4
// 298.151 us; speedup vs baseline: 3.5619x; 3.4264x over previous
//
#include <hip/hip_runtime.h>
#include <hip/hip_bf16.h>
#include <cstdint>
#include <cstddef>

#define NB   8
#define CIN  128
#define COUT 64
#define HH   128
#define WWD  128
#define NPIX (NB*HH*WWD)   // 131072
#define PLANE NPIX

typedef _Float16 f16;
typedef _Float16 half2_t __attribute__((ext_vector_type(2)));
typedef _Float16 half8_t __attribute__((ext_vector_type(8)));
typedef float    float4_t __attribute__((ext_vector_type(4)));

// ============ Kernel 0: pack W1|W2|W3 into f16 [192 rows][128 cols] ============
__global__ __launch_bounds__(256) void wsetup_k(
    const float* __restrict__ W1, const float* __restrict__ W2,
    const float* __restrict__ W3, f16* __restrict__ Wf)
{
  int idx = blockIdx.x * 256 + threadIdx.x;      // 0 .. 24575
  int mat = idx >> 13;                           // /8192
  int rem = idx & 8191;
  const float* src = (mat == 0 ? W1 : (mat == 1 ? W2 : W3));
  Wf[idx] = (f16)src[rem];
}

// ============ Kernel 1: 1x1 convs as one f16 MFMA GEMM ============
// C[M=128 px][N=192 cout] = x_tile[128 px][128 c] * W^T ; per block: 128-px tile.
// A-frag (x) from LDS [px][c](+8 pad); B-frag (W) from global; 4 waves x 2 mtiles x 12 ntiles.
// Outputs Q/K/V as f16 interleaved [g=c/8][PLANE][8].
__global__ __launch_bounds__(256) void conv_mfma_k(
    const float* __restrict__ x, const f16* __restrict__ Wf,
    f16* __restrict__ Qi, f16* __restrict__ Ki, f16* __restrict__ Vi)
{
  __shared__ f16 xs[128 * 136];                  // 34.8 KB, row stride 136 (16B-aligned, padded)

  int tid  = threadIdx.x;
  int lane = tid & 63;
  int wv   = tid >> 6;
  int pxt  = blockIdx.x * 128;
  int n    = pxt >> 14;
  int hwt  = pxt & 16383;

  // ---- stage x[c][px] fp32 -> LDS [px][c] f16 ----
  {
    int pxl  = tid & 127;
    int chal = (tid >> 7) * 64;                  // this thread's 64-channel half
    const float* xp = x + ((size_t)(n * CIN + chal) << 14) + hwt + pxl;
    #pragma unroll
    for (int c0 = 0; c0 < 64; c0 += 8) {
      half8_t hh;
      #pragma unroll
      for (int j = 0; j < 8; ++j)
        hh[j] = (f16)xp[(size_t)(c0 + j) << 14]; // coalesced dword loads, 64KB ch stride
      *(half8_t*)&xs[pxl * 136 + chal + c0] = hh; // b128, 2-way bank (free)
    }
  }
  __syncthreads();

  // ---- MFMA main loop ----
  float4_t acc[2][12];
  #pragma unroll
  for (int mt = 0; mt < 2; ++mt)
    #pragma unroll
    for (int nt = 0; nt < 12; ++nt)
      acc[mt][nt] = (float4_t){0.f, 0.f, 0.f, 0.f};

  int l15 = lane & 15, q4 = lane >> 4;
  #pragma unroll
  for (int k0 = 0; k0 < 128; k0 += 32) {
    half8_t a0 = *(half8_t*)&xs[((wv*2 + 0)*16 + l15) * 136 + k0 + q4*8];
    half8_t a1 = *(half8_t*)&xs[((wv*2 + 1)*16 + l15) * 136 + k0 + q4*8];
    #pragma unroll
    for (int nt = 0; nt < 12; ++nt) {
      half8_t b = *(const half8_t*)&Wf[(nt*16 + l15) * 128 + k0 + q4*8];
      acc[0][nt] = __builtin_amdgcn_mfma_f32_16x16x32_f16(a0, b, acc[0][nt], 0, 0, 0);
      acc[1][nt] = __builtin_amdgcn_mfma_f32_16x16x32_f16(a1, b, acc[1][nt], 0, 0, 0);
    }
  }

  // ---- epilogue: C row=px=(lane>>4)*4+reg, col=cout=lane&15 -> [g][px][8] f16 ----
  int l7 = lane & 7, gh = l15 >> 3;
  #pragma unroll
  for (int mt = 0; mt < 2; ++mt) {
    int pxg = pxt + (wv*2 + mt)*16 + q4*4;
    #pragma unroll
    for (int nt = 0; nt < 12; ++nt) {
      f16* base = (nt < 4 ? Qi : (nt < 8 ? Ki : Vi));
      int g = (nt & 3)*2 + gh;
      f16* p = base + ((size_t)g * PLANE) * 8 + l7;
      #pragma unroll
      for (int r = 0; r < 4; ++r)
        p[(size_t)(pxg + r) * 8] = (f16)acc[mt][nt][r];  // 2 full 64B lines / instr
    }
  }
}

// ============ Kernel 2: logits (fdot2) + online softmax; L stored fp32 ============
__global__ __launch_bounds__(256) void logits2_k(
    const f16* __restrict__ Qi, const f16* __restrict__ Ki,
    float* __restrict__ Lp, float* __restrict__ Mp, float* __restrict__ Sp)
{
  int px = blockIdx.x * 256 + threadIdx.x;
  int n = px >> 14, hw = px & 16383, h = hw >> 7, w = hw & 127;

  half2_t q[32];
  #pragma unroll
  for (int g = 0; g < 8; ++g) {
    half8_t v = *(const half8_t*)&Qi[((size_t)g * PLANE + px) * 8];
    q[g*4+0] = (half2_t){v[0], v[1]};
    q[g*4+1] = (half2_t){v[2], v[3]};
    q[g*4+2] = (half2_t){v[4], v[5]};
    q[g*4+3] = (half2_t){v[6], v[7]};
  }

  float m = -1e30f, s = 0.f;
  int nb = n << 14;

  for (int dh = 0; dh < 9; ++dh) {
    int hs = h + 2*dh - 8;
    bool rv = ((unsigned)hs < 128u);             // wave-uniform (64 | row)
    for (int dw = 0; dw < 9; ++dw) {
      float l = 0.f;
      if (rv) {
        int ws_ = w + 2*dw - 8;                  // per-lane; mem stays in-bounds (guards in ws)
        int pxn = nb + (hs << 7) + ws_;
        const f16* kp = Ki + (size_t)pxn * 8;
        float d0 = 0.f, d1 = 0.f, d2 = 0.f, d3 = 0.f;
        #pragma unroll
        for (int g = 0; g < 8; ++g) {
          half8_t kv = *(const half8_t*)&kp[(size_t)g * PLANE * 8];  // dense 16B/lane
          d0 = __builtin_amdgcn_fdot2((half2_t){kv[0], kv[1]}, q[g*4+0], d0, false);
          d1 = __builtin_amdgcn_fdot2((half2_t){kv[2], kv[3]}, q[g*4+1], d1, false);
          d2 = __builtin_amdgcn_fdot2((half2_t){kv[4], kv[5]}, q[g*4+2], d2, false);
          d3 = __builtin_amdgcn_fdot2((half2_t){kv[6], kv[7]}, q[g*4+3], d3, false);
        }
        float d = (d0 + d1) + (d2 + d3);
        l = ((unsigned)ws_ < 128u) ? d : 0.f;    // OOB window -> logit exactly 0
      }
      float mn = fmaxf(m, l);                    // online softmax
      s = s * __expf(m - mn) + __expf(l - mn);
      m = mn;
      Lp[(size_t)(dh*9 + dw) * PLANE + px] = l;  // fp32, coalesced
    }
  }
  Mp[px] = m;
  Sp[px] = 1.f / s;
}

// ============ Kernel 3: apply weights to V; thread = (px, 32-ch half) ============
__global__ __launch_bounds__(256) void apply2_k(
    const f16* __restrict__ Vi, const float* __restrict__ Lp,
    const float* __restrict__ Mp, const float* __restrict__ Sp,
    float* __restrict__ out)
{
  int t    = threadIdx.x;
  int pxl  = t & 127;
  int half = t >> 7;
  int px   = blockIdx.x * 128 + pxl;
  int n = px >> 14, hw = px & 16383, h = hw >> 7, w = hw & 127;

  float m = Mp[px], sinv = Sp[px];
  float acc[32];
  #pragma unroll
  for (int j = 0; j < 32; ++j) acc[j] = 0.f;
  int nb = n << 14;

  for (int dh = 0; dh < 9; ++dh) {
    int hs = h + 2*dh - 8;
    if ((unsigned)hs >= 128u) continue;          // uniform per block (1 image row/block)
    for (int dw = 0; dw < 9; ++dw) {
      int ws_ = w + 2*dw - 8;
      bool val = ((unsigned)ws_ < 128u);
      float l = Lp[(size_t)(dh*9 + dw) * PLANE + px];
      float wgt = val ? __expf(l - m) * sinv : 0.f;
      int pxn = val ? (nb + (hs << 7) + ws_) : px;
      const f16* vp = Vi + ((size_t)(half*4) * PLANE + pxn) * 8;
      #pragma unroll
      for (int j = 0; j < 4; ++j) {
        half8_t vv = *(const half8_t*)&vp[(size_t)j * PLANE * 8];
        #pragma unroll
        for (int e = 0; e < 8; ++e)
          acc[j*8 + e] = fmaf(wgt, (float)vv[e], acc[j*8 + e]);  // v_fma_mix
      }
    }
  }
  size_t ob = ((size_t)(n*COUT + half*32) << 14) + hw;  // NCHW, coalesced
  #pragma unroll
  for (int j = 0; j < 32; ++j) out[ob + ((size_t)j << 14)] = acc[j];
}

// ---------------- launcher ----------------
extern "C" void kernel_launch(void* const* d_in, const int* in_sizes, int n_in,
                              void* d_out, int out_size, void* d_ws, size_t ws_size,
                              hipStream_t stream)
{
  const float* x  = (const float*)d_in[0];
  const float* W1 = (const float*)d_in[1];
  const float* W2 = (const float*)d_in[2];
  const float* W3 = (const float*)d_in[3];

  // ws layout (~94 MB). Lp first so Ki/Vi reads with negative px offsets stay in ws.
  float* Lp = (float*)d_ws;                                  // [81][PLANE] fp32
  float* Mp = Lp + (size_t)81 * PLANE;                       // [PLANE]
  float* Sp = Mp + PLANE;                                    // [PLANE]
  f16*   Wf = (f16*)(Sp + PLANE);                            // [192][128] f16
  f16*   Qi = Wf + (size_t)192 * 128;                        // [8][PLANE][8] f16
  f16*   Ki = Qi + (size_t)8 * PLANE * 8;
  f16*   Vi = Ki + (size_t)8 * PLANE * 8;                    // (+128B OOB slack fits in ws)

  float* outp = (float*)d_out;

  wsetup_k   <<<96,        256, 0, stream>>>(W1, W2, W3, Wf);
  conv_mfma_k<<<NPIX/128,  256, 0, stream>>>(x, Wf, Qi, Ki, Vi);
  logits2_k  <<<NPIX/256,  256, 0, stream>>>(Qi, Ki, Lp, Mp, Sp);
  apply2_k   <<<NPIX/128,  256, 0, stream>>>(Vi, Lp, Mp, Sp, outp);
}

// Round 5
// 217.826 us; speedup vs baseline: 4.8754x; 1.3688x over previous
//
#include <hip/hip_runtime.h>
#include <hip/hip_bf16.h>
#include <cstdint>
#include <cstddef>

#define NB   8
#define CIN  128
#define COUT 64
#define HH   128
#define WWD  128
#define NPIX (NB*HH*WWD)   // 131072
#define PLANE NPIX

typedef _Float16 f16;
typedef _Float16 half8_t __attribute__((ext_vector_type(8)));
typedef float    float4_t __attribute__((ext_vector_type(4)));

// ============ Kernel 0: pack W1|W2|W3 into f16 [192 rows][128 cols] ============
__global__ __launch_bounds__(256) void wsetup_k(
    const float* __restrict__ W1, const float* __restrict__ W2,
    const float* __restrict__ W3, f16* __restrict__ Wf)
{
  int idx = blockIdx.x * 256 + threadIdx.x;      // 0 .. 24575
  int mat = idx >> 13;
  int rem = idx & 8191;
  const float* src = (mat == 0 ? W1 : (mat == 1 ? W2 : W3));
  Wf[idx] = (f16)src[rem];
}

// ============ Kernel 1: 1x1 convs as one f16 MFMA GEMM ============
// Q,K out: interleaved [g=c/8][PLANE][8] f16 (A/B-frag friendly: 16B per (px,g)).
// V out: planar [c][PLANE] f16 (PV B-frag friendly: px-contiguous).
__global__ __launch_bounds__(256) void conv_mfma_k(
    const float* __restrict__ x, const f16* __restrict__ Wf,
    f16* __restrict__ Qi, f16* __restrict__ Ki, f16* __restrict__ V2)
{
  __shared__ f16 xs[128 * 136];

  int tid  = threadIdx.x;
  int lane = tid & 63;
  int wv   = tid >> 6;
  int pxt  = blockIdx.x * 128;
  int n    = pxt >> 14;
  int hwt  = pxt & 16383;

  // stage x[c][px] fp32 -> LDS [px][c] f16
  {
    int pxl  = tid & 127;
    int chal = (tid >> 7) * 64;
    const float* xp = x + ((size_t)(n * CIN + chal) << 14) + hwt + pxl;
    #pragma unroll
    for (int c0 = 0; c0 < 64; c0 += 8) {
      half8_t hh;
      #pragma unroll
      for (int j = 0; j < 8; ++j)
        hh[j] = (f16)xp[(size_t)(c0 + j) << 14];
      *(half8_t*)&xs[pxl * 136 + chal + c0] = hh;
    }
  }
  __syncthreads();

  float4_t acc[2][12];
  #pragma unroll
  for (int mt = 0; mt < 2; ++mt)
    #pragma unroll
    for (int nt = 0; nt < 12; ++nt)
      acc[mt][nt] = (float4_t){0.f, 0.f, 0.f, 0.f};

  int l15 = lane & 15, q4 = lane >> 4;
  #pragma unroll
  for (int k0 = 0; k0 < 128; k0 += 32) {
    half8_t a0 = *(half8_t*)&xs[((wv*2 + 0)*16 + l15) * 136 + k0 + q4*8];
    half8_t a1 = *(half8_t*)&xs[((wv*2 + 1)*16 + l15) * 136 + k0 + q4*8];
    #pragma unroll
    for (int nt = 0; nt < 12; ++nt) {
      half8_t b = *(const half8_t*)&Wf[(nt*16 + l15) * 128 + k0 + q4*8];
      acc[0][nt] = __builtin_amdgcn_mfma_f32_16x16x32_f16(a0, b, acc[0][nt], 0, 0, 0);
      acc[1][nt] = __builtin_amdgcn_mfma_f32_16x16x32_f16(a1, b, acc[1][nt], 0, 0, 0);
    }
  }

  // epilogue: C row=px=(lane>>4)*4+reg, col=cout=lane&15
  int l7 = lane & 7, gh = l15 >> 3;
  #pragma unroll
  for (int mt = 0; mt < 2; ++mt) {
    int pxg = pxt + (wv*2 + mt)*16 + q4*4;
    #pragma unroll
    for (int nt = 0; nt < 12; ++nt) {
      if (nt < 8) {                                  // Q,K interleaved [g][px][8]
        f16* base = (nt < 4 ? Qi : Ki);
        int g = (nt & 3)*2 + gh;
        f16* p = base + ((size_t)g * PLANE) * 8 + l7;
        #pragma unroll
        for (int r = 0; r < 4; ++r)
          p[(size_t)(pxg + r) * 8] = (f16)acc[mt][nt][r];
      } else {                                       // V planar [c][PLANE]
        int cout = (nt & 3)*16 + l15;
        f16* p = V2 + (size_t)cout * PLANE;
        #pragma unroll
        for (int r = 0; r < 4; ++r)
          p[pxg + r] = (f16)acc[mt][nt][r];
      }
    }
  }
}

// ============ Kernel 2: fused flash local attention ============
// Block = 1 image row (n,h), 4 waves; wave w: 32-px segment. Per dh (valid rows only):
// S[32x48] = Q.K^T via MFMA -> band/parity/bounds mask -> online softmax (rows in C-layout,
// shfl_xor over lane&15) -> P f16 -> LDS transpose (C-layout -> A-layout, cols 48..63 zero)
// -> O += P x V via MFMA. OOB offsets' logit-0 mass merged in closed form at the end.
__global__ __launch_bounds__(256) void attn_fused_k(
    const f16* __restrict__ Qi, const f16* __restrict__ Ki,
    const f16* __restrict__ V2, float* __restrict__ out)
{
  __shared__ f16 plds[4][32 * 72];                   // per-wave P tile, row stride 72

  int tid = threadIdx.x, lane = tid & 63, wv = tid >> 6;
  int l15 = lane & 15, q4 = lane >> 4;
  int n = blockIdx.x >> 7, h = blockIdx.x & 127;
  int seg = wv * 32;
  int base = (n << 14) + (h << 7) + seg;

  f16* P = &plds[wv][0];
  // zero cols 48..63 once (never rewritten -> padded K for the 2nd PV mfma)
  *(half8_t*)&P[(lane >> 1) * 72 + 48 + (lane & 1) * 8] = (half8_t){0,0,0,0,0,0,0,0};

  // Q A-frags
  half8_t aq[2][2];
  #pragma unroll
  for (int mt = 0; mt < 2; ++mt) {
    int pxq = base + mt*16 + l15;
    aq[mt][0] = *(const half8_t*)&Qi[((size_t)q4       * PLANE + pxq) * 8];
    aq[mt][1] = *(const half8_t*)&Qi[((size_t)(q4 + 4) * PLANE + pxq) * 8];
  }

  // dh-invariant validity mask: 24 bits, bit = (mt*3+nt)*4 + r
  unsigned vbits = 0;
  #pragma unroll
  for (int mt = 0; mt < 2; ++mt)
    #pragma unroll
    for (int nt = 0; nt < 3; ++nt)
      #pragma unroll
      for (int r = 0; r < 4; ++r) {
        int iw = seg + mt*16 + q4*4 + r;
        int jw = seg - 8 + nt*16 + l15;
        int d  = jw - iw;
        bool val = (((d & 1) == 0) & (d >= -8) & (d <= 8) & ((unsigned)jw < 128u));
        vbits |= ((unsigned)val) << ((mt*3 + nt)*4 + r);
      }

  float mrow[2][4], lrow[2][4];
  float4_t o_[2][4];
  #pragma unroll
  for (int mt = 0; mt < 2; ++mt)
    #pragma unroll
    for (int r = 0; r < 4; ++r) { mrow[mt][r] = -1e30f; lrow[mt][r] = 0.f; }
  #pragma unroll
  for (int mt = 0; mt < 2; ++mt)
    #pragma unroll
    for (int ct = 0; ct < 4; ++ct) o_[mt][ct] = (float4_t){0.f,0.f,0.f,0.f};

  int dhlo = (9 - h) >> 1;   if (dhlo < 0) dhlo = 0;
  int dhhi = (135 - h) >> 1; if (dhhi > 8) dhhi = 8;
  int vh = dhhi - dhlo + 1;

  for (int dh = dhlo; dh <= dhhi; ++dh) {
    int hs = h + 2*dh - 8;                           // in [0,127]
    int jbase = (n << 14) + (hs << 7) + seg - 8;     // col-0 px (mem-safe: +-128B in ws)

    // K B-frags (16B contiguous per (g,px))
    half8_t bk[3][2];
    #pragma unroll
    for (int nt = 0; nt < 3; ++nt) {
      int pxj = jbase + nt*16 + l15;
      bk[nt][0] = *(const half8_t*)&Ki[((size_t)q4       * PLANE + pxj) * 8];
      bk[nt][1] = *(const half8_t*)&Ki[((size_t)(q4 + 4) * PLANE + pxj) * 8];
    }

    // S = Q.K^T
    float4_t s[2][3];
    #pragma unroll
    for (int mt = 0; mt < 2; ++mt)
      #pragma unroll
      for (int nt = 0; nt < 3; ++nt) {
        float4_t t = (float4_t){0.f,0.f,0.f,0.f};
        t = __builtin_amdgcn_mfma_f32_16x16x32_f16(aq[mt][0], bk[nt][0], t, 0, 0, 0);
        t = __builtin_amdgcn_mfma_f32_16x16x32_f16(aq[mt][1], bk[nt][1], t, 0, 0, 0);
        s[mt][nt] = t;
      }

    // mask invalid entries to -1e30
    #pragma unroll
    for (int mt = 0; mt < 2; ++mt)
      #pragma unroll
      for (int nt = 0; nt < 3; ++nt)
        #pragma unroll
        for (int r = 0; r < 4; ++r)
          s[mt][nt][r] = ((vbits >> ((mt*3 + nt)*4 + r)) & 1u) ? s[mt][nt][r] : -1e30f;

    // online softmax: row max/sum (reduce 3 nt + shfl over l15), rescale O
    float al[2][4];
    #pragma unroll
    for (int mt = 0; mt < 2; ++mt)
      #pragma unroll
      for (int r = 0; r < 4; ++r) {
        float v = fmaxf(fmaxf(s[mt][0][r], s[mt][1][r]), s[mt][2][r]);
        v = fmaxf(v, __shfl_xor(v, 1, 64));
        v = fmaxf(v, __shfl_xor(v, 2, 64));
        v = fmaxf(v, __shfl_xor(v, 4, 64));
        v = fmaxf(v, __shfl_xor(v, 8, 64));
        float mn = fmaxf(mrow[mt][r], v);
        al[mt][r] = __expf(mrow[mt][r] - mn);
        mrow[mt][r] = mn;
      }
    #pragma unroll
    for (int mt = 0; mt < 2; ++mt)
      #pragma unroll
      for (int nt = 0; nt < 3; ++nt)
        #pragma unroll
        for (int r = 0; r < 4; ++r)
          s[mt][nt][r] = __expf(s[mt][nt][r] - mrow[mt][r]);   // masked -> exp(-1e30)=0
    #pragma unroll
    for (int mt = 0; mt < 2; ++mt)
      #pragma unroll
      for (int r = 0; r < 4; ++r) {
        float rs = s[mt][0][r] + s[mt][1][r] + s[mt][2][r];
        rs += __shfl_xor(rs, 1, 64);
        rs += __shfl_xor(rs, 2, 64);
        rs += __shfl_xor(rs, 4, 64);
        rs += __shfl_xor(rs, 8, 64);
        lrow[mt][r] = lrow[mt][r] * al[mt][r] + rs;
      }
    #pragma unroll
    for (int mt = 0; mt < 2; ++mt)
      #pragma unroll
      for (int ct = 0; ct < 4; ++ct)
        #pragma unroll
        for (int r = 0; r < 4; ++r)
          o_[mt][ct][r] *= al[mt][r];

    // P -> LDS (C-layout write)
    #pragma unroll
    for (int mt = 0; mt < 2; ++mt)
      #pragma unroll
      for (int nt = 0; nt < 3; ++nt)
        #pragma unroll
        for (int r = 0; r < 4; ++r)
          P[(mt*16 + q4*4 + r) * 72 + nt*16 + l15] = (f16)s[mt][nt][r];

    // P A-frags (A-layout read; cols 48..63 are the zero pad)
    half8_t ap[2][2];
    #pragma unroll
    for (int mt = 0; mt < 2; ++mt) {
      ap[mt][0] = *(half8_t*)&P[(mt*16 + l15) * 72 +      q4*8];
      ap[mt][1] = *(half8_t*)&P[(mt*16 + l15) * 72 + 32 + q4*8];
    }

    // O += P x V
    #pragma unroll
    for (int ct = 0; ct < 4; ++ct) {
      const f16* vb = V2 + (size_t)(ct*16 + l15) * PLANE + jbase;
      half8_t bv0 = *(const half8_t*)&vb[q4*8];
      half8_t bv1 = *(const half8_t*)&vb[32 + q4*8];
      #pragma unroll
      for (int mt = 0; mt < 2; ++mt) {
        o_[mt][ct] = __builtin_amdgcn_mfma_f32_16x16x32_f16(ap[mt][0], bv0, o_[mt][ct], 0, 0, 0);
        o_[mt][ct] = __builtin_amdgcn_mfma_f32_16x16x32_f16(ap[mt][1], bv1, o_[mt][ct], 0, 0, 0);
      }
    }
  }

  // epilogue: fold OOB logit-0 mass (m=0, l=cnt_oob), normalize, store NCHW
  #pragma unroll
  for (int mt = 0; mt < 2; ++mt) {
    float sc[4];
    #pragma unroll
    for (int r = 0; r < 4; ++r) {
      int iw = seg + mt*16 + q4*4 + r;
      int dwlo = (9 - iw) >> 1;   if (dwlo < 0) dwlo = 0;
      int dwhi = (135 - iw) >> 1; if (dwhi > 8) dwhi = 8;
      int cnt = 81 - vh * (dwhi - dwlo + 1);
      float m = mrow[mt][r], l = lrow[mt][r];
      float mn = fmaxf(m, 0.f);
      float em = __expf(m - mn);
      sc[r] = em / (l * em + (float)cnt * __expf(-mn));
    }
    #pragma unroll
    for (int ct = 0; ct < 4; ++ct) {
      size_t ob = ((size_t)(n*COUT + ct*16 + l15) << 14) + (h << 7) + seg + mt*16 + q4*4;
      #pragma unroll
      for (int r = 0; r < 4; ++r)
        out[ob + r] = o_[mt][ct][r] * sc[r];
    }
  }
}

// ---------------- launcher ----------------
extern "C" void kernel_launch(void* const* d_in, const int* in_sizes, int n_in,
                              void* d_out, int out_size, void* d_ws, size_t ws_size,
                              hipStream_t stream)
{
  const float* x  = (const float*)d_in[0];
  const float* W1 = (const float*)d_in[1];
  const float* W2 = (const float*)d_in[2];
  const float* W3 = (const float*)d_in[3];

  // ws: Wf | Qi | Ki | V2  (~50.4 MB; edge reads overrun +-128B into neighbors/tail -> safe,
  // masked to zero weight before use)
  f16* Wf = (f16*)d_ws;                              // [192][128]
  f16* Qi = Wf + (size_t)192 * 128;                  // [8][PLANE][8]
  f16* Ki = Qi + (size_t)8 * PLANE * 8;              // [8][PLANE][8]
  f16* V2 = Ki + (size_t)8 * PLANE * 8;              // [64][PLANE]

  float* outp = (float*)d_out;

  wsetup_k   <<<96,       256, 0, stream>>>(W1, W2, W3, Wf);
  conv_mfma_k<<<NPIX/128, 256, 0, stream>>>(x, Wf, Qi, Ki, V2);
  attn_fused_k<<<NB*HH,   256, 0, stream>>>(Qi, Ki, V2, outp);
}

// Round 6
// 194.201 us; speedup vs baseline: 5.4685x; 1.1217x over previous
//
#include <hip/hip_runtime.h>
#include <hip/hip_bf16.h>
#include <cstdint>
#include <cstddef>

#define NB   8
#define CIN  128
#define COUT 64
#define HH   128
#define WWD  128
#define NPIX (NB*HH*WWD)   // 131072
#define PLANE NPIX

typedef _Float16 f16;
typedef _Float16 half4_t __attribute__((ext_vector_type(4)));
typedef _Float16 half8_t __attribute__((ext_vector_type(8)));
typedef float    float4_t __attribute__((ext_vector_type(4)));

// ============ Kernel 0: pack W1|W2|W3 into f16 [192 rows][128 cols] ============
__global__ __launch_bounds__(256) void wsetup_k(
    const float* __restrict__ W1, const float* __restrict__ W2,
    const float* __restrict__ W3, f16* __restrict__ Wf)
{
  int idx = blockIdx.x * 256 + threadIdx.x;      // 0 .. 24575
  int mat = idx >> 13;
  int rem = idx & 8191;
  const float* src = (mat == 0 ? W1 : (mat == 1 ? W2 : W3));
  Wf[idx] = (f16)src[rem];
}

// ============ Kernel 1: 1x1 convs as one f16 MFMA GEMM ============
// Operand-swap epilogue trick: Q/K tiles computed as D[cout][px] (mfma(W,x)),
// V tiles as D[px][cout] (mfma(x,W)) -> all stores are b64 vectors.
// Q,K out: interleaved [g=c/8][PLANE][8] f16; V out: planar [c][PLANE] f16.
__global__ __launch_bounds__(256) void conv_mfma_k(
    const float* __restrict__ x, const f16* __restrict__ Wf,
    f16* __restrict__ Qi, f16* __restrict__ Ki, f16* __restrict__ V2)
{
  __shared__ f16 xs[128 * 136];

  int tid  = threadIdx.x;
  int lane = tid & 63;
  int wv   = tid >> 6;
  int pxt  = blockIdx.x * 128;
  int n    = pxt >> 14;
  int hwt  = pxt & 16383;

  // stage x[c][px] fp32 -> LDS [px][c] f16
  {
    int pxl  = tid & 127;
    int chal = (tid >> 7) * 64;
    const float* xp = x + ((size_t)(n * CIN + chal) << 14) + hwt + pxl;
    #pragma unroll
    for (int c0 = 0; c0 < 64; c0 += 8) {
      half8_t hh;
      #pragma unroll
      for (int j = 0; j < 8; ++j)
        hh[j] = (f16)xp[(size_t)(c0 + j) << 14];
      *(half8_t*)&xs[pxl * 136 + chal + c0] = hh;
    }
  }
  __syncthreads();

  float4_t acc[2][12];
  #pragma unroll
  for (int mt = 0; mt < 2; ++mt)
    #pragma unroll
    for (int nt = 0; nt < 12; ++nt)
      acc[mt][nt] = (float4_t){0.f, 0.f, 0.f, 0.f};

  int l15 = lane & 15, q4 = lane >> 4;
  #pragma unroll
  for (int k0 = 0; k0 < 128; k0 += 32) {
    // x fragments (serve as B for Q/K tiles, A for V tiles)
    half8_t xa0 = *(half8_t*)&xs[(wv*32 +      l15) * 136 + k0 + q4*8];
    half8_t xa1 = *(half8_t*)&xs[(wv*32 + 16 + l15) * 136 + k0 + q4*8];
    #pragma unroll
    for (int nt = 0; nt < 12; ++nt) {
      half8_t wb = *(const half8_t*)&Wf[(nt*16 + l15) * 128 + k0 + q4*8];
      if (nt < 8) {      // Q,K: D[cout][px]
        acc[0][nt] = __builtin_amdgcn_mfma_f32_16x16x32_f16(wb, xa0, acc[0][nt], 0, 0, 0);
        acc[1][nt] = __builtin_amdgcn_mfma_f32_16x16x32_f16(wb, xa1, acc[1][nt], 0, 0, 0);
      } else {           // V: D[px][cout]
        acc[0][nt] = __builtin_amdgcn_mfma_f32_16x16x32_f16(xa0, wb, acc[0][nt], 0, 0, 0);
        acc[1][nt] = __builtin_amdgcn_mfma_f32_16x16x32_f16(xa1, wb, acc[1][nt], 0, 0, 0);
      }
    }
  }

  // epilogue: all b64 stores
  int pxseg = pxt + wv*32;
  #pragma unroll
  for (int mt = 0; mt < 2; ++mt) {
    int pxq = pxseg + mt*16 + l15;        // Q/K: col = px
    #pragma unroll
    for (int nt = 0; nt < 8; ++nt) {
      f16* base = (nt < 4) ? Qi : Ki;
      int g = (nt & 3)*2 + (q4 >> 1);     // cout = (nt&3)*16 + q4*4 + r
      half4_t v = {(f16)acc[mt][nt][0], (f16)acc[mt][nt][1],
                   (f16)acc[mt][nt][2], (f16)acc[mt][nt][3]};
      *(half4_t*)&base[((size_t)g * PLANE + pxq) * 8 + (q4 & 1)*4] = v;
    }
    int pxv = pxseg + mt*16 + q4*4;       // V: row = px (4 consecutive)
    #pragma unroll
    for (int nt = 8; nt < 12; ++nt) {
      int cout = (nt - 8)*16 + l15;
      half4_t v = {(f16)acc[mt][nt][0], (f16)acc[mt][nt][1],
                   (f16)acc[mt][nt][2], (f16)acc[mt][nt][3]};
      *(half4_t*)&V2[(size_t)cout * PLANE + pxv] = v;
    }
  }
}

// ============ Kernel 2: fused flash local attention (S^T formulation) ============
// XCD swizzle: n = b&7 pins image k to XCD k (K/V stream stays in that XCD's L2).
// Per dh: S^T[48 j][32 i] = K.Q^T via mfma(K,Q); softmax stats in-lane over j
// (+2 shfls over q4); P written [i][j] as b64; O += P.V with rows = i -> float4 out.
__global__ __launch_bounds__(256) void attn_fused_k(
    const f16* __restrict__ Qi, const f16* __restrict__ Ki,
    const f16* __restrict__ V2, float* __restrict__ out)
{
  __shared__ f16   plds[4][32 * 72];
  __shared__ float alds[4][32];

  int tid = threadIdx.x, lane = tid & 63, wv = tid >> 6;
  int l15 = lane & 15, q4 = lane >> 4;
  int n = blockIdx.x & 7, h = (blockIdx.x >> 3) & 127;   // XCD swizzle
  int seg = wv * 32;
  int base = (n << 14) + (h << 7) + seg;

  f16*   P    = &plds[wv][0];
  float* albc = &alds[wv][0];
  // zero P cols 48..63 once (padded K for 2nd PV mfma)
  *(half8_t*)&P[(lane >> 1) * 72 + 48 + (lane & 1) * 8] = (half8_t){0,0,0,0,0,0,0,0};

  // Q B-frags (n = i = l15)
  half8_t aq[2][2];
  #pragma unroll
  for (int it = 0; it < 2; ++it) {
    int pxq = base + it*16 + l15;
    aq[it][0] = *(const half8_t*)&Qi[((size_t)q4       * PLANE + pxq) * 8];
    aq[it][1] = *(const half8_t*)&Qi[((size_t)(q4 + 4) * PLANE + pxq) * 8];
  }

  // dh-invariant validity mask for S^T: bit = (jt*2+it)*4 + r; lane j = q4*4+r, i = l15
  unsigned vbits = 0;
  #pragma unroll
  for (int jt = 0; jt < 3; ++jt)
    #pragma unroll
    for (int it = 0; it < 2; ++it)
      #pragma unroll
      for (int r = 0; r < 4; ++r) {
        int jw = seg - 8 + jt*16 + q4*4 + r;
        int iw = seg + it*16 + l15;
        int d  = jw - iw;
        bool val = (((d & 1) == 0) & (d >= -8) & (d <= 8) & ((unsigned)jw < 128u));
        vbits |= ((unsigned)val) << ((jt*2 + it)*4 + r);
      }

  float mrow[2] = {-1e30f, -1e30f}, lrow[2] = {0.f, 0.f};
  float4_t o_[2][4];                                   // [it][ct], rows = i
  #pragma unroll
  for (int it = 0; it < 2; ++it)
    #pragma unroll
    for (int ct = 0; ct < 4; ++ct) o_[it][ct] = (float4_t){0.f,0.f,0.f,0.f};

  int dhlo = (9 - h) >> 1;   if (dhlo < 0) dhlo = 0;
  int dhhi = (135 - h) >> 1; if (dhhi > 8) dhhi = 8;
  int vh = dhhi - dhlo + 1;

  for (int dh = dhlo; dh <= dhhi; ++dh) {
    int hs = h + 2*dh - 8;                             // in [0,127]
    int jbase = (n << 14) + (hs << 7) + seg - 8;

    // K A-frags (m = j)
    half8_t bk[3][2];
    #pragma unroll
    for (int jt = 0; jt < 3; ++jt) {
      int pxj = jbase + jt*16 + l15;
      bk[jt][0] = *(const half8_t*)&Ki[((size_t)q4       * PLANE + pxj) * 8];
      bk[jt][1] = *(const half8_t*)&Ki[((size_t)(q4 + 4) * PLANE + pxj) * 8];
    }

    // S^T = K.Q^T
    float4_t s[3][2];
    #pragma unroll
    for (int jt = 0; jt < 3; ++jt)
      #pragma unroll
      for (int it = 0; it < 2; ++it) {
        float4_t t = (float4_t){0.f,0.f,0.f,0.f};
        t = __builtin_amdgcn_mfma_f32_16x16x32_f16(bk[jt][0], aq[it][0], t, 0, 0, 0);
        t = __builtin_amdgcn_mfma_f32_16x16x32_f16(bk[jt][1], aq[it][1], t, 0, 0, 0);
        s[jt][it] = t;
      }

    // mask
    #pragma unroll
    for (int jt = 0; jt < 3; ++jt)
      #pragma unroll
      for (int it = 0; it < 2; ++it)
        #pragma unroll
        for (int r = 0; r < 4; ++r)
          s[jt][it][r] = ((vbits >> ((jt*2 + it)*4 + r)) & 1u) ? s[jt][it][r] : -1e30f;

    // online softmax: stats over j are in-lane (12 vals) + 2 shfls across q4
    float al2[2];
    #pragma unroll
    for (int it = 0; it < 2; ++it) {
      float v = -1e30f;
      #pragma unroll
      for (int jt = 0; jt < 3; ++jt)
        #pragma unroll
        for (int r = 0; r < 4; ++r) v = fmaxf(v, s[jt][it][r]);
      v = fmaxf(v, __shfl_xor(v, 16, 64));
      v = fmaxf(v, __shfl_xor(v, 32, 64));
      float mn = fmaxf(mrow[it], v);
      al2[it] = __expf(mrow[it] - mn);
      mrow[it] = mn;
      albc[it*16 + l15] = al2[it];                     // same value from all q4
    }
    #pragma unroll
    for (int jt = 0; jt < 3; ++jt)
      #pragma unroll
      for (int it = 0; it < 2; ++it)
        #pragma unroll
        for (int r = 0; r < 4; ++r)
          s[jt][it][r] = __expf(s[jt][it][r] - mrow[it]);  // masked -> 0
    #pragma unroll
    for (int it = 0; it < 2; ++it) {
      float rs = 0.f;
      #pragma unroll
      for (int jt = 0; jt < 3; ++jt)
        #pragma unroll
        for (int r = 0; r < 4; ++r) rs += s[jt][it][r];
      rs += __shfl_xor(rs, 16, 64);
      rs += __shfl_xor(rs, 32, 64);
      lrow[it] = lrow[it] * al2[it] + rs;
    }

    // P[i][j] b64 writes (lane: 4 consecutive j for i = l15)
    #pragma unroll
    for (int jt = 0; jt < 3; ++jt)
      #pragma unroll
      for (int it = 0; it < 2; ++it) {
        half4_t pv = {(f16)s[jt][it][0], (f16)s[jt][it][1],
                      (f16)s[jt][it][2], (f16)s[jt][it][3]};
        *(half4_t*)&P[(it*16 + l15)*72 + jt*16 + q4*4] = pv;
      }

    // rescale O by al (broadcast al[i] for i = q4*4+r)
    float4_t alv[2];
    #pragma unroll
    for (int it = 0; it < 2; ++it)
      alv[it] = *(float4_t*)&albc[it*16 + q4*4];
    #pragma unroll
    for (int it = 0; it < 2; ++it)
      #pragma unroll
      for (int ct = 0; ct < 4; ++ct)
        #pragma unroll
        for (int r = 0; r < 4; ++r)
          o_[it][ct][r] *= alv[it][r];

    // P A-frags + O += P.V
    half8_t ap[2][2];
    #pragma unroll
    for (int it = 0; it < 2; ++it) {
      ap[it][0] = *(half8_t*)&P[(it*16 + l15)*72 +      q4*8];
      ap[it][1] = *(half8_t*)&P[(it*16 + l15)*72 + 32 + q4*8];
    }
    #pragma unroll
    for (int ct = 0; ct < 4; ++ct) {
      const f16* vb = V2 + (size_t)(ct*16 + l15) * PLANE + jbase;
      half8_t bv0 = *(const half8_t*)&vb[q4*8];
      half8_t bv1 = *(const half8_t*)&vb[32 + q4*8];
      #pragma unroll
      for (int it = 0; it < 2; ++it) {
        o_[it][ct] = __builtin_amdgcn_mfma_f32_16x16x32_f16(ap[it][0], bv0, o_[it][ct], 0, 0, 0);
        o_[it][ct] = __builtin_amdgcn_mfma_f32_16x16x32_f16(ap[it][1], bv1, o_[it][ct], 0, 0, 0);
      }
    }
  }

  // epilogue: fold OOB logit-0 mass, broadcast per-i scale, float4 stores
  #pragma unroll
  for (int it = 0; it < 2; ++it) {
    int iw = seg + it*16 + l15;
    int dwlo = (9 - iw) >> 1;   if (dwlo < 0) dwlo = 0;
    int dwhi = (135 - iw) >> 1; if (dwhi > 8) dwhi = 8;
    int cnt = 81 - vh * (dwhi - dwlo + 1);
    float m = mrow[it], l = lrow[it];
    float mn = fmaxf(m, 0.f);
    float em = __expf(m - mn);
    albc[it*16 + l15] = em / (l * em + (float)cnt * __expf(-mn));
  }
  float4_t scv[2];
  #pragma unroll
  for (int it = 0; it < 2; ++it)
    scv[it] = *(float4_t*)&albc[it*16 + q4*4];
  #pragma unroll
  for (int it = 0; it < 2; ++it)
    #pragma unroll
    for (int ct = 0; ct < 4; ++ct) {
      size_t ob = ((size_t)(n*COUT + ct*16 + l15) << 14) + (h << 7) + seg + it*16 + q4*4;
      float4_t stv;
      #pragma unroll
      for (int r = 0; r < 4; ++r) stv[r] = o_[it][ct][r] * scv[it][r];
      *(float4_t*)&out[ob] = stv;
    }
}

// ---------------- launcher ----------------
extern "C" void kernel_launch(void* const* d_in, const int* in_sizes, int n_in,
                              void* d_out, int out_size, void* d_ws, size_t ws_size,
                              hipStream_t stream)
{
  const float* x  = (const float*)d_in[0];
  const float* W1 = (const float*)d_in[1];
  const float* W2 = (const float*)d_in[2];
  const float* W3 = (const float*)d_in[3];

  // ws: Wf | Qi | Ki | V2 (~50.4 MB; +-128B edge read overruns stay in ws, masked)
  f16* Wf = (f16*)d_ws;                              // [192][128]
  f16* Qi = Wf + (size_t)192 * 128;                  // [8][PLANE][8]
  f16* Ki = Qi + (size_t)8 * PLANE * 8;              // [8][PLANE][8]
  f16* V2 = Ki + (size_t)8 * PLANE * 8;              // [64][PLANE]

  float* outp = (float*)d_out;

  wsetup_k    <<<96,       256, 0, stream>>>(W1, W2, W3, Wf);
  conv_mfma_k <<<NPIX/128, 256, 0, stream>>>(x, Wf, Qi, Ki, V2);
  attn_fused_k<<<NB*HH,    256, 0, stream>>>(Qi, Ki, V2, outp);
}

// Round 7
// 158.967 us; speedup vs baseline: 6.6805x; 1.2216x over previous
//
#include <hip/hip_runtime.h>
#include <hip/hip_bf16.h>
#include <cstdint>
#include <cstddef>

#define NB   8
#define CIN  128
#define COUT 64
#define HH   128
#define WWD  128
#define NPIX (NB*HH*WWD)   // 131072
#define PLANE NPIX
#define LOG2E 1.44269504088896340736f

typedef _Float16 f16;
typedef _Float16 half4_t __attribute__((ext_vector_type(4)));
typedef _Float16 half8_t __attribute__((ext_vector_type(8)));
typedef float    float4_t __attribute__((ext_vector_type(4)));

// ============ Kernel 0: pack W1|W2|W3 -> f16 [192][128]; W1 pre-scaled by log2e ============
__global__ __launch_bounds__(256) void wsetup_k(
    const float* __restrict__ W1, const float* __restrict__ W2,
    const float* __restrict__ W3, f16* __restrict__ Wf)
{
  int idx = blockIdx.x * 256 + threadIdx.x;      // 0 .. 24575
  int mat = idx >> 13;
  int rem = idx & 8191;
  const float* src = (mat == 0 ? W1 : (mat == 1 ? W2 : W3));
  float v = src[rem];
  if (mat == 0) v *= LOG2E;                      // logits become base-2 -> exp2 in attn
  Wf[idx] = (f16)v;
}

// ============ Kernel 1: 1x1 convs, W-stationary MFMA ============
// Block 256 = 4 waves, 64-px tile. Wave wv owns nt {wv, wv+4, wv+8} (Q/K/V 16-cout strips):
// 12 W-frags preloaded once; per mt: 4 LDS x-frags serve all 3 MFMA chains; epilogue inlined.
__global__ __launch_bounds__(256, 4) void conv_mfma_k(
    const float* __restrict__ x, const f16* __restrict__ Wf,
    f16* __restrict__ Qi, f16* __restrict__ Ki, f16* __restrict__ V2)
{
  __shared__ __align__(16) f16 xs[64 * 136];     // 17.4 KB

  int tid = threadIdx.x, lane = tid & 63, wv = tid >> 6;
  int pxt = blockIdx.x * 64;
  int n = pxt >> 14, hwt = pxt & 16383;

  // stage x[c][px] fp32 -> LDS [px][c] f16 (wave wv: channel strip wv*32)
  {
    const float* xp = x + ((size_t)(n * CIN + wv * 32) << 14) + hwt + lane;
    #pragma unroll
    for (int c0 = 0; c0 < 32; c0 += 8) {
      half8_t hh;
      #pragma unroll
      for (int j = 0; j < 8; ++j)
        hh[j] = (f16)xp[(size_t)(c0 + j) << 14];
      *(half8_t*)&xs[lane * 136 + wv * 32 + c0] = hh;
    }
  }
  __syncthreads();

  int l15 = lane & 15, q4 = lane >> 4;

  // preload W frags (reused across all mt)
  half8_t wq[4], wk[4], wvf[4];
  #pragma unroll
  for (int k0 = 0; k0 < 4; ++k0) {
    wq[k0]  = *(const half8_t*)&Wf[((wv     )*16 + l15)*128 + k0*32 + q4*8];
    wk[k0]  = *(const half8_t*)&Wf[((wv +  4)*16 + l15)*128 + k0*32 + q4*8];
    wvf[k0] = *(const half8_t*)&Wf[((wv +  8)*16 + l15)*128 + k0*32 + q4*8];
  }

  #pragma unroll
  for (int mt = 0; mt < 4; ++mt) {
    float4_t cq = {0.f,0.f,0.f,0.f}, ck = {0.f,0.f,0.f,0.f}, cv = {0.f,0.f,0.f,0.f};
    #pragma unroll
    for (int k0 = 0; k0 < 4; ++k0) {
      half8_t xa = *(half8_t*)&xs[(mt*16 + l15)*136 + k0*32 + q4*8];
      cq = __builtin_amdgcn_mfma_f32_16x16x32_f16(wq[k0],  xa, cq, 0, 0, 0); // D[cout][px]
      ck = __builtin_amdgcn_mfma_f32_16x16x32_f16(wk[k0],  xa, ck, 0, 0, 0); // D[cout][px]
      cv = __builtin_amdgcn_mfma_f32_16x16x32_f16(xa, wvf[k0], cv, 0, 0, 0); // D[px][cout]
    }
    // epilogue (per mt, keeps acc live-range tiny)
    int pxq = pxt + mt*16 + l15;                 // Q/K: col = px
    int g   = wv*2 + (q4 >> 1);                  // cout = wv*16 + q4*4 + r
    half4_t hq = {(f16)cq[0], (f16)cq[1], (f16)cq[2], (f16)cq[3]};
    half4_t hk = {(f16)ck[0], (f16)ck[1], (f16)ck[2], (f16)ck[3]};
    *(half4_t*)&Qi[((size_t)g * PLANE + pxq) * 8 + (q4 & 1)*4] = hq;
    *(half4_t*)&Ki[((size_t)g * PLANE + pxq) * 8 + (q4 & 1)*4] = hk;
    // V: planar [cout][px], row = px = q4*4+r
    half4_t hv = {(f16)cv[0], (f16)cv[1], (f16)cv[2], (f16)cv[3]};
    *(half4_t*)&V2[(size_t)(wv*16 + l15) * PLANE + pxt + mt*16 + q4*4] = hv;
  }
}

// ============ Kernel 2: fused flash local attention, row-paired ============
// Block 512 = 8 waves; wave = 16-px segment of rows (h0, h0+2) (same parity -> shared
// K/V rows). Per hs (10 iters): load K/V frags once, run both rows' S^T->softmax->PV.
// j-window = 32 = exact MFMA K (no padding). exp2 (logits pre-scaled by log2e via W1).
__global__ __launch_bounds__(512, 4) void attn_fused_k(
    const f16* __restrict__ Qi, const f16* __restrict__ Ki,
    const f16* __restrict__ V2, float* __restrict__ out)
{
  __shared__ __align__(16) f16 plds[8][2][16 * 40];   // 20.5 KB

  int tid = threadIdx.x, lane = tid & 63, wv = tid >> 6;
  int l15 = lane & 15, q4 = lane >> 4;
  int b = blockIdx.x;
  int n = b & 7;                                  // XCD swizzle: image n -> XCD n
  int p = b >> 3;                                 // 0..63
  int h0 = (p >> 1)*4 + (p & 1);                  // rows h0, h0+2 cover all h
  int h2 = h0 + 2;
  int seg = wv * 16;
  int nb = n << 14;

  f16* P0 = &plds[wv][0][0];
  f16* P1 = &plds[wv][1][0];

  // Q B-frags for both rows (n-dim = i = l15)
  half8_t aq0[2], aq1[2];
  {
    int px0 = nb + (h0 << 7) + seg + l15;
    aq0[0] = *(const half8_t*)&Qi[((size_t)(q4    ) * PLANE + px0) * 8];
    aq0[1] = *(const half8_t*)&Qi[((size_t)(q4 + 4) * PLANE + px0) * 8];
    int px1 = px0 + 256;
    aq1[0] = *(const half8_t*)&Qi[((size_t)(q4    ) * PLANE + px1) * 8];
    aq1[1] = *(const half8_t*)&Qi[((size_t)(q4 + 4) * PLANE + px1) * 8];
  }

  // dh-invariant validity: bit jt*4+r; lane j = seg-8+jt*16+q4*4+r, i = seg+l15
  unsigned vbits = 0;
  #pragma unroll
  for (int jt = 0; jt < 2; ++jt)
    #pragma unroll
    for (int r = 0; r < 4; ++r) {
      int jw = seg - 8 + jt*16 + q4*4 + r;
      int iw = seg + l15;
      int d  = jw - iw;
      bool val = (((d & 1) == 0) & (d >= -8) & (d <= 8) & ((unsigned)jw < 128u));
      vbits |= ((unsigned)val) << (jt*4 + r);
    }

  float m0 = -1e30f, s0 = 0.f, m1 = -1e30f, s1 = 0.f;
  float4_t o0[4], o1[4];
  #pragma unroll
  for (int ct = 0; ct < 4; ++ct) {
    o0[ct] = (float4_t){0.f,0.f,0.f,0.f};
    o1[ct] = (float4_t){0.f,0.f,0.f,0.f};
  }

  auto row_body = [&](const half8_t* aq, float& m, float& l,
                      float4_t* o, f16* P, const half8_t (&bk)[2][2],
                      const half8_t (&bv)[4]) {
    // S^T[32 j][16 i] = K.Q^T
    float4_t st0 = (float4_t){0.f,0.f,0.f,0.f};
    float4_t st1 = (float4_t){0.f,0.f,0.f,0.f};
    st0 = __builtin_amdgcn_mfma_f32_16x16x32_f16(bk[0][0], aq[0], st0, 0, 0, 0);
    st0 = __builtin_amdgcn_mfma_f32_16x16x32_f16(bk[0][1], aq[1], st0, 0, 0, 0);
    st1 = __builtin_amdgcn_mfma_f32_16x16x32_f16(bk[1][0], aq[0], st1, 0, 0, 0);
    st1 = __builtin_amdgcn_mfma_f32_16x16x32_f16(bk[1][1], aq[1], st1, 0, 0, 0);
    #pragma unroll
    for (int r = 0; r < 4; ++r) {
      st0[r] = ((vbits >> r)       & 1u) ? st0[r] : -1e30f;
      st1[r] = ((vbits >> (4 + r)) & 1u) ? st1[r] : -1e30f;
    }
    // row max (in-lane 8 + shfl over q4)
    float v = fmaxf(fmaxf(fmaxf(st0[0], st0[1]), fmaxf(st0[2], st0[3])),
                    fmaxf(fmaxf(st1[0], st1[1]), fmaxf(st1[2], st1[3])));
    v = fmaxf(v, __shfl_xor(v, 16, 64));
    v = fmaxf(v, __shfl_xor(v, 32, 64));
    float mn = fmaxf(m, v);
    float al = exp2f(m - mn);
    m = mn;
    #pragma unroll
    for (int r = 0; r < 4; ++r) {
      st0[r] = exp2f(st0[r] - mn);                 // masked -> 0
      st1[r] = exp2f(st1[r] - mn);
    }
    float rs = (st0[0] + st0[1]) + (st0[2] + st0[3])
             + (st1[0] + st1[1]) + (st1[2] + st1[3]);
    rs += __shfl_xor(rs, 16, 64);
    rs += __shfl_xor(rs, 32, 64);
    l = l * al + rs;
    // broadcast al to o-rows (i = q4*4+r lives at stats-lane l15' = q4*4+r)
    float4_t alv;
    #pragma unroll
    for (int r = 0; r < 4; ++r) alv[r] = __shfl(al, q4*4 + r, 64);
    #pragma unroll
    for (int ct = 0; ct < 4; ++ct)
      #pragma unroll
      for (int r = 0; r < 4; ++r) o[ct][r] *= alv[r];
    // P[i][j]: C-layout write (half4), A-layout read (half8) — same-wave LDS roundtrip
    half4_t p0 = {(f16)st0[0], (f16)st0[1], (f16)st0[2], (f16)st0[3]};
    half4_t p1 = {(f16)st1[0], (f16)st1[1], (f16)st1[2], (f16)st1[3]};
    *(half4_t*)&P[l15*40      + q4*4] = p0;
    *(half4_t*)&P[l15*40 + 16 + q4*4] = p1;
    half8_t ap = *(half8_t*)&P[l15*40 + q4*8];
    #pragma unroll
    for (int ct = 0; ct < 4; ++ct)
      o[ct] = __builtin_amdgcn_mfma_f32_16x16x32_f16(ap, bv[ct], o[ct], 0, 0, 0);
  };

  for (int hs = h0 - 8; hs <= h0 + 10; hs += 2) {
    if (hs < 0 || hs > 127) continue;              // wave-uniform
    bool a0 = (hs <= h0 + 8);
    bool a1 = (hs >= h0 - 6);
    int jbase = nb + (hs << 7) + seg - 8;          // mem-safe: +-128B stays in ws

    half8_t bk[2][2];
    #pragma unroll
    for (int jt = 0; jt < 2; ++jt) {
      int pxj = jbase + jt*16 + l15;
      bk[jt][0] = *(const half8_t*)&Ki[((size_t)(q4    ) * PLANE + pxj) * 8];
      bk[jt][1] = *(const half8_t*)&Ki[((size_t)(q4 + 4) * PLANE + pxj) * 8];
    }
    half8_t bv[4];
    #pragma unroll
    for (int ct = 0; ct < 4; ++ct)
      bv[ct] = *(const half8_t*)&V2[(size_t)(ct*16 + l15) * PLANE + jbase + q4*8];

    if (a0) row_body(aq0, m0, s0, o0, P0, bk, bv);
    if (a1) row_body(aq1, m1, s1, o1, P1, bk, bv);
  }

  // epilogue: fold OOB logit-0 mass (base-2: logit 0 -> exp2(0)), scale, float4 store
  int iw = seg + l15;
  int wlo = iw - 8; if (wlo < 0) wlo = 0;
  int whi = iw + 8; if (whi > 127) whi = 127;
  int vw = ((whi - wlo) >> 1) + 1;
  #pragma unroll
  for (int row = 0; row < 2; ++row) {
    int hr = row ? h2 : h0;
    int hlo = hr - 8; if (hlo < 0) hlo = 0;
    int hhi = hr + 8; if (hhi > 127) hhi = 127;
    int vh = ((hhi - hlo) >> 1) + 1;
    float cnt = (float)(81 - vh * vw);
    float m = row ? m1 : m0, l = row ? s1 : s0;
    float mn = fmaxf(m, 0.f);
    float em = exp2f(m - mn);
    float sc = em / (l * em + cnt * exp2f(-mn));
    float4_t scv;
    #pragma unroll
    for (int r = 0; r < 4; ++r) scv[r] = __shfl(sc, q4*4 + r, 64);
    const float4_t* o = row ? o1 : o0;
    #pragma unroll
    for (int ct = 0; ct < 4; ++ct) {
      size_t ob = ((size_t)(n*COUT + ct*16 + l15) << 14) + (hr << 7) + seg + q4*4;
      float4_t stv;
      #pragma unroll
      for (int r = 0; r < 4; ++r) stv[r] = o[ct][r] * scv[r];
      *(float4_t*)&out[ob] = stv;
    }
  }
}

// ---------------- launcher ----------------
extern "C" void kernel_launch(void* const* d_in, const int* in_sizes, int n_in,
                              void* d_out, int out_size, void* d_ws, size_t ws_size,
                              hipStream_t stream)
{
  const float* x  = (const float*)d_in[0];
  const float* W1 = (const float*)d_in[1];
  const float* W2 = (const float*)d_in[2];
  const float* W3 = (const float*)d_in[3];

  // ws: Wf | Qi | Ki | V2 (~50.4 MB; +-128B edge overruns stay inside ws, masked to 0 weight)
  f16* Wf = (f16*)d_ws;                              // [192][128]
  f16* Qi = Wf + (size_t)192 * 128;                  // [8][PLANE][8] (ch-group interleaved)
  f16* Ki = Qi + (size_t)8 * PLANE * 8;              // [8][PLANE][8]
  f16* V2 = Ki + (size_t)8 * PLANE * 8;              // [64][PLANE] planar

  float* outp = (float*)d_out;

  wsetup_k    <<<96,       256, 0, stream>>>(W1, W2, W3, Wf);
  conv_mfma_k <<<NPIX/64,  256, 0, stream>>>(x, Wf, Qi, Ki, V2);
  attn_fused_k<<<NB*HH/2,  512, 0, stream>>>(Qi, Ki, V2, outp);
}